// Round 4
// baseline (478.677 us; speedup 1.0000x reference)
//
#include <hip/hip_runtime.h>
#include <math.h>

#define NROWS 16384
#define DDIM  4096
#define NEXP  64
#define TOPK  8
#define RPW   4          // rows per wave
#define CHUNK 8          // k elements per chunk (2 x float4)

// Bit-exact emulation of the numpy reference (verified round 3):
//  - einsum SSE1 path: 4 mod-4 fp32 partials, ascending k, separate mul/add
//    rounding, final (s0+s1)+(s2+s3)
//  - softmax: fp32 max-subtract, double-exp rounded to f32, pairwise-8 row sum
//  - top-8 on fp32 probs, ties -> lower index; gates = v / (seq-sum + 1e-9)
//
// Structure: lane = expert (64 lanes = 64 experts), each wave owns 4 rows
// completely -> no LDS, no __syncthreads, wave-independent. x row chunks are
// wave-uniform (scalar/broadcast loads, each 64B line used fully, read once);
// W is per-lane divergent but 1 MB total -> L1/L2 resident.

#define LOADC(kk, A0_, A1_, B0_, B1_) do {                                   \
    _Pragma("unroll")                                                        \
    for (int r_ = 0; r_ < RPW; ++r_) {                                       \
        A0_[r_] = *(const float4*)(xr + (size_t)r_ * DDIM + (kk));           \
        A1_[r_] = *(const float4*)(xr + (size_t)r_ * DDIM + (kk) + 4);       \
    }                                                                        \
    B0_ = *(const float4*)(wr + (kk));                                       \
    B1_ = *(const float4*)(wr + (kk) + 4);                                   \
} while (0)

// chunk holds k0..k7; partial p accumulates k === p (mod 4), ascending:
// p gets k_p then k_{p+4} -- sequential adds preserve the np chain order.
#define COMPUTEC(A0_, A1_, B0_, B1_) do {                                    \
    _Pragma("unroll")                                                        \
    for (int r_ = 0; r_ < RPW; ++r_) {                                       \
        s[r_][0] = __fadd_rn(s[r_][0], __fmul_rn(A0_[r_].x, B0_.x));         \
        s[r_][1] = __fadd_rn(s[r_][1], __fmul_rn(A0_[r_].y, B0_.y));         \
        s[r_][2] = __fadd_rn(s[r_][2], __fmul_rn(A0_[r_].z, B0_.z));         \
        s[r_][3] = __fadd_rn(s[r_][3], __fmul_rn(A0_[r_].w, B0_.w));         \
        s[r_][0] = __fadd_rn(s[r_][0], __fmul_rn(A1_[r_].x, B1_.x));         \
        s[r_][1] = __fadd_rn(s[r_][1], __fmul_rn(A1_[r_].y, B1_.y));         \
        s[r_][2] = __fadd_rn(s[r_][2], __fmul_rn(A1_[r_].z, B1_.z));         \
        s[r_][3] = __fadd_rn(s[r_][3], __fmul_rn(A1_[r_].w, B1_.w));         \
    }                                                                        \
} while (0)

__global__ __launch_bounds__(256) void router_reg(const float* __restrict__ x,
                                                  const float* __restrict__ W,
                                                  float* __restrict__ out) {
    const int lane = threadIdx.x & 63;
    const int wv   = __builtin_amdgcn_readfirstlane((int)(threadIdx.x >> 6));
    const int row0 = (blockIdx.x * 4 + wv) * RPW;

    const float* xr = x + (size_t)row0 * DDIM;   // wave-uniform
    const float* wr = W + (size_t)lane * DDIM;   // per-lane (expert)

    float s[RPW][4];
    #pragma unroll
    for (int r = 0; r < RPW; ++r)
        #pragma unroll
        for (int p = 0; p < 4; ++p) s[r][p] = 0.f;

    float4 A0[RPW], A1[RPW], B0, B1;      // current chunk
    float4 nA0[RPW], nA1[RPW], nB0, nB1;  // next chunk

    LOADC(0, A0, A1, B0, B1);
    int k = 0;
    for (; k + 2 * CHUNK < DDIM; k += 2 * CHUNK) {
        LOADC(k + CHUNK, nA0, nA1, nB0, nB1);      // prefetch chunk k+8
        COMPUTEC(A0, A1, B0, B1);                  // compute chunk k
        LOADC(k + 2 * CHUNK, A0, A1, B0, B1);      // prefetch chunk k+16
        COMPUTEC(nA0, nA1, nB0, nB1);              // compute chunk k+8
    }
    // k == DDIM - 2*CHUNK here; cur buffer holds chunk k
    LOADC(k + CHUNK, nA0, nA1, nB0, nB1);
    COMPUTEC(A0, A1, B0, B1);
    COMPUTEC(nA0, nA1, nB0, nB1);

    // ---- epilogue: per-row softmax + top-k, wave-private ----
    float* out_gates = out;
    float* out_idx   = out + (size_t)NROWS * TOPK;
    float* out_probs = out + (size_t)NROWS * TOPK * 2;

    #pragma unroll
    for (int r = 0; r < RPW; ++r) {
        // numpy einsum reduction tree: (s0+s1)+(s2+s3)
        const float l = __fadd_rn(__fadd_rn(s[r][0], s[r][1]),
                                  __fadd_rn(s[r][2], s[r][3]));

        // max over 64 fp32 logits (order-independent)
        float m = l;
        #pragma unroll
        for (int off = 32; off > 0; off >>= 1)
            m = fmaxf(m, __shfl_xor(m, off));

        // e = exp(l - m): fp32 subtract, near-correctly-rounded fp32 exp
        const float e = (float)exp((double)__fsub_rn(l, m));

        // numpy pairwise-8 row sum
        const int j8 = lane & 7;
        float rsum = __shfl(e, j8);
        #pragma unroll
        for (int t = 1; t < 8; ++t)
            rsum = __fadd_rn(rsum, __shfl(e, j8 + t * 8));
        const float r0 = __shfl(rsum, 0), r1 = __shfl(rsum, 1);
        const float r2 = __shfl(rsum, 2), r3 = __shfl(rsum, 3);
        const float r4 = __shfl(rsum, 4), r5 = __shfl(rsum, 5);
        const float r6 = __shfl(rsum, 6), r7 = __shfl(rsum, 7);
        const float S = __fadd_rn(__fadd_rn(__fadd_rn(r0, r1), __fadd_rn(r2, r3)),
                                  __fadd_rn(__fadd_rn(r4, r5), __fadd_rn(r6, r7)));

        const float prob = __fdiv_rn(e, S);

        const size_t grow = (size_t)(row0 + r);
        out_probs[grow * NEXP + lane] = prob;

        // top-8 on fp32 probs; ties -> lower index
        float work = prob;
        float myval = 0.f, topsum = 0.f;
        int   myidx = 0;
        for (int it = 0; it < TOPK; ++it) {
            float v = work;
            int   idx = lane;
            #pragma unroll
            for (int off = 32; off > 0; off >>= 1) {
                float ov = __shfl_xor(v, off);
                int   oi = __shfl_xor(idx, off);
                if (ov > v || (ov == v && oi < idx)) { v = ov; idx = oi; }
            }
            const float pw = __shfl(prob, idx);
            topsum = __fadd_rn(topsum, pw);   // rank-order sequential sum
            if (lane == idx) work = -1.0f;    // exclude winner
            if (lane == it)  { myval = pw; myidx = idx; }
        }
        if (lane < TOPK) {
            out_gates[grow * TOPK + lane] = __fdiv_rn(myval, __fadd_rn(topsum, 1e-9f));
            out_idx[grow * TOPK + lane]   = (float)myidx;
        }
    }
}

extern "C" void kernel_launch(void* const* d_in, const int* in_sizes, int n_in,
                              void* d_out, int out_size, void* d_ws, size_t ws_size,
                              hipStream_t stream) {
    const float* x = (const float*)d_in[0];   // (16384, 4096) fp32
    const float* W = (const float*)d_in[1];   // (64, 4096) fp32
    float* out = (float*)d_out;               // gates(N*8) | indices(N*8) | probs(N*64)

    dim3 grid(NROWS / (4 * RPW));  // 1024 blocks (4 waves x 4 rows each)
    dim3 block(256);
    hipLaunchKernelGGL(router_reg, grid, block, 0, stream, x, W, out);
}